// Round 7
// baseline (3171.621 us; speedup 1.0000x reference)
//
#include <hip/hip_runtime.h>
#include <hip/hip_fp16.h>

// 2-layer GCN: out = gcn(relu(gcn(x,W1,b1,e0)), W2, b2, e1)
// R1-R5: CSR build evolved to: LDS chunk-sort scatter (write-amp 1.0) +
//   bucket run tables + transpose; H' = (XW)*dinv stored fp16.
// R6: node-level CSR order is unnecessary (aggregation is a sum). bfin ->
//   bfin2: ONE pass, runs copied to bucket-contiguous packed2 (window
//   offsets from an LDS scan of run lengths -- no per-node cursors), node
//   degrees counted in LDS -> dinv. csr/off arrays deleted. agg -> aggp:
//   block-per-bucket PUSH into a 32KB LDS fp32 accumulator (bank-swizzled,
//   seeded with self-loop), edges stream coalesced from packed2, gathers
//   use half2 dual-edge (2 rows / VMEM instr).

#define NPB   128
#define BSH   7
#define BMSK  127
#define MAXB  1024          // >= B = ceil(100000/128) = 782
#define ROST  (MAXB + 1)    // runoff row stride
#define CHUNK 4096
#define MAXCH 1024          // >= nchunk = ceil(E/CHUNK) = 782

// Sort chunk k by dst-bucket entirely in LDS; write packed[] coalesced.
__global__ __launch_bounds__(256) void k_scatter(const int* __restrict__ src,
                                                 const int* __restrict__ dst,
                                                 int* __restrict__ runoff,
                                                 int* __restrict__ btot,
                                                 int* __restrict__ packed,
                                                 int E, int B) {
  __shared__ int stage[CHUNK];
  __shared__ int sorted[CHUNK];
  __shared__ unsigned short bkt[CHUNK];
  __shared__ int hist[MAXB];
  __shared__ int wsum[4];
  int t = threadIdx.x;
  int k = blockIdx.x;
  int e0 = k * CHUNK;
  int cnt = min(CHUNK, E - e0);
  for (int b = t; b < B; b += 256) hist[b] = 0;
  __syncthreads();
  if (cnt == CHUNK) {
#pragma unroll
    for (int r = 0; r < 16; r += 4) {
      int i0 = (r + 0) * 256 + t, i1 = (r + 1) * 256 + t;
      int i2 = (r + 2) * 256 + t, i3 = (r + 3) * 256 + t;
      int d0 = dst[e0 + i0], d1 = dst[e0 + i1];
      int d2 = dst[e0 + i2], d3 = dst[e0 + i3];
      int s0 = src[e0 + i0], s1 = src[e0 + i1];
      int s2 = src[e0 + i2], s3 = src[e0 + i3];
      stage[i0] = (s0 << BSH) | (d0 & BMSK); bkt[i0] = (unsigned short)(d0 >> BSH);
      stage[i1] = (s1 << BSH) | (d1 & BMSK); bkt[i1] = (unsigned short)(d1 >> BSH);
      stage[i2] = (s2 << BSH) | (d2 & BMSK); bkt[i2] = (unsigned short)(d2 >> BSH);
      stage[i3] = (s3 << BSH) | (d3 & BMSK); bkt[i3] = (unsigned short)(d3 >> BSH);
      atomicAdd(&hist[d0 >> BSH], 1);
      atomicAdd(&hist[d1 >> BSH], 1);
      atomicAdd(&hist[d2 >> BSH], 1);
      atomicAdd(&hist[d3 >> BSH], 1);
    }
  } else {
    for (int i = t; i < cnt; i += 256) {
      int d = dst[e0 + i], s = src[e0 + i];
      stage[i] = (s << BSH) | (d & BMSK);
      bkt[i] = (unsigned short)(d >> BSH);
      atomicAdd(&hist[d >> BSH], 1);
    }
  }
  __syncthreads();
  int i0 = t * 4;
  int v0 = (i0 + 0 < B) ? hist[i0 + 0] : 0;
  int v1 = (i0 + 1 < B) ? hist[i0 + 1] : 0;
  int v2 = (i0 + 2 < B) ? hist[i0 + 2] : 0;
  int v3 = (i0 + 3 < B) ? hist[i0 + 3] : 0;
  if (v0) atomicAdd(&btot[i0 + 0], v0);
  if (v1) atomicAdd(&btot[i0 + 1], v1);
  if (v2) atomicAdd(&btot[i0 + 2], v2);
  if (v3) atomicAdd(&btot[i0 + 3], v3);
  int tsum = v0 + v1 + v2 + v3;
  int lane = t & 63, wid = t >> 6;
  int x = tsum;
#pragma unroll
  for (int d = 1; d < 64; d <<= 1) {
    int y = __shfl_up(x, d, 64);
    if (lane >= d) x += y;
  }
  if (lane == 63) wsum[wid] = x;
  __syncthreads();
  int wofs = 0;
  for (int ww = 0; ww < wid; ++ww) wofs += wsum[ww];
  int excl = wofs + x - tsum;
  hist[i0 + 0] = excl;
  hist[i0 + 1] = excl + v0;
  hist[i0 + 2] = excl + v0 + v1;
  hist[i0 + 3] = excl + v0 + v1 + v2;
  __syncthreads();
  int* row = runoff + (size_t)k * ROST;
  for (int b = t; b < B; b += 256) row[b] = hist[b];
  if (t == 0) row[B] = cnt;
  __syncthreads();
  for (int i = t; i < cnt; i += 256) {
    int pos = atomicAdd(&hist[bkt[i]], 1);
    sorted[pos] = stage[i];
  }
  __syncthreads();
  for (int i = t; i < cnt; i += 256) packed[e0 + i] = sorted[i];
}

// Exclusive scan of bucket totals -> bbase[0..B], bbase[B]=E. One block.
__global__ __launch_bounds__(1024) void k_btot(const int* __restrict__ btot,
                                               int* __restrict__ bbase,
                                               int B, int E) {
  __shared__ int wsum[16];
  int t = threadIdx.x;
  int c = (t < B) ? btot[t] : 0;
  int lane = t & 63, wid = t >> 6;
  int x = c;
#pragma unroll
  for (int d = 1; d < 64; d <<= 1) {
    int y = __shfl_up(x, d, 64);
    if (lane >= d) x += y;
  }
  if (lane == 63) wsum[wid] = x;
  __syncthreads();
  int wofs = 0;
  for (int ww = 0; ww < wid; ++ww) wofs += wsum[ww];
  if (t < B) bbase[t] = wofs + x - c;
  if (t == 0) bbase[B] = E;
}

// Tiled transpose: AT[b][k] = A[k][b].
__global__ __launch_bounds__(256) void k_transpose(const int* __restrict__ A,
                                                   int* __restrict__ AT,
                                                   int rows, int cols) {
  __shared__ int tile[32][33];
  int bx = blockIdx.x * 32;
  int by = blockIdx.y * 32;
  int tx = threadIdx.x & 31, ty = threadIdx.x >> 5;
#pragma unroll
  for (int q = 0; q < 4; ++q) {
    int r = by + ty + q * 8, c = bx + tx;
    if (r < rows && c < cols) tile[ty + q * 8][tx] = A[(size_t)r * ROST + c];
  }
  __syncthreads();
#pragma unroll
  for (int q = 0; q < 4; ++q) {
    int c = bx + ty + q * 8;
    int r = by + tx;
    if (c < cols && r < rows) AT[(size_t)c * MAXCH + r] = tile[tx][ty + q * 8];
  }
}

// Per-bucket finalize, ONE pass: scan run lengths -> copy runs into
// bucket-contiguous packed2 window; count node degrees in LDS -> dinv.
__global__ __launch_bounds__(256) void k_bfin2(const int* __restrict__ packed,
                                               const int* __restrict__ runoffT,
                                               const int* __restrict__ bbase,
                                               float* __restrict__ dinv,
                                               int* __restrict__ packed2,
                                               int N, int B, int nchunk) {
  __shared__ int rs[MAXCH];
  __shared__ unsigned short rl[MAXCH];
  __shared__ int pref[MAXCH];
  __shared__ int cnt[NPB];
  __shared__ int wsum[4];
  int t = threadIdx.x;
  int b = blockIdx.x;
  for (int k = t; k < nchunk; k += 256) {
    int s = runoffT[(size_t)b * MAXCH + k];
    int e = runoffT[(size_t)(b + 1) * MAXCH + k];
    rs[k] = k * CHUNK + s;
    rl[k] = (unsigned short)(e - s);
  }
  if (t < NPB) cnt[t] = 0;
  __syncthreads();
  // block scan of run lengths (256 threads x 4 = 1024 >= nchunk)
  int i0 = t * 4;
  int v0 = (i0 + 0 < nchunk) ? rl[i0 + 0] : 0;
  int v1 = (i0 + 1 < nchunk) ? rl[i0 + 1] : 0;
  int v2 = (i0 + 2 < nchunk) ? rl[i0 + 2] : 0;
  int v3 = (i0 + 3 < nchunk) ? rl[i0 + 3] : 0;
  int tsum = v0 + v1 + v2 + v3;
  int lane = t & 63, w = t >> 6;
  int x = tsum;
#pragma unroll
  for (int d = 1; d < 64; d <<= 1) {
    int y = __shfl_up(x, d, 64);
    if (lane >= d) x += y;
  }
  if (lane == 63) wsum[w] = x;
  __syncthreads();
  int wofs = 0;
  for (int ww = 0; ww < w; ++ww) wofs += wsum[ww];
  int excl = wofs + x - tsum;
  pref[i0 + 0] = excl;
  pref[i0 + 1] = excl + v0;
  pref[i0 + 2] = excl + v0 + v1;
  pref[i0 + 3] = excl + v0 + v1 + v2;
  __syncthreads();
  // copy runs -> packed2 window; count degrees on the fly
  int wbase = bbase[b];
  for (int k = t; k < nchunk; k += 256) {
    int base = rs[k], len = rl[k];
    int o = wbase + pref[k];
    for (int j = 0; j < len; ++j) {
      int e = packed[base + j];
      atomicAdd(&cnt[e & BMSK], 1);
      packed2[o + j] = e;
    }
  }
  __syncthreads();
  if (t < NPB) {
    int v = (b << BSH) + t;
    if (v < N) dinv[v] = rsqrtf((float)(cnt[t] + 1));  // +1 self-loop
  }
}

// H'[v] = fp16((X @ W)[v] * dinv[v]).  W (16KB) in LDS; 4 nodes/block-iter.
__global__ __launch_bounds__(256) void k_gemm64(const float* __restrict__ X,
                                                const float* __restrict__ W,
                                                const float* __restrict__ dinv,
                                                __half* __restrict__ H, int N) {
  __shared__ float Wl[4096];
  __shared__ float Xl[256];
  for (int t = threadIdx.x; t < 4096; t += 256) Wl[t] = W[t];
  int j = threadIdx.x & 63;
  int nl = threadIdx.x >> 6;
  for (int base = blockIdx.x * 4; base < N; base += gridDim.x * 4) {
    __syncthreads();
    int gi = base * 64 + threadIdx.x;
    Xl[threadIdx.x] = (gi < N * 64) ? X[gi] : 0.f;
    __syncthreads();
    int v = base + nl;
    if (v < N) {
      float acc = 0.f;
#pragma unroll
      for (int k = 0; k < 64; k += 4) {
        acc = fmaf(Xl[nl * 64 + k + 0], Wl[(k + 0) * 64 + j], acc);
        acc = fmaf(Xl[nl * 64 + k + 1], Wl[(k + 1) * 64 + j], acc);
        acc = fmaf(Xl[nl * 64 + k + 2], Wl[(k + 2) * 64 + j], acc);
        acc = fmaf(Xl[nl * 64 + k + 3], Wl[(k + 3) * 64 + j], acc);
      }
      H[v * 64 + j] = __float2half_rn(acc * dinv[v]);
    }
  }
}

// Push aggregation: block-per-bucket, 32KB LDS fp32 accumulator.
// Swizzled layout: feature f of node dl lives at acc[dl*64 + ((f&1)<<5) + (f>>1)]
// -> half2 dual-edge ds_add hits 32 distinct banks (2-way wave64, free).
// Edges stream coalesced from packed2; lanes 0-31 take edge j, 32-63 edge j+1.
template <bool RELU>
__global__ __launch_bounds__(256) void k_aggp(const __half* __restrict__ H,
                                              const int* __restrict__ packed2,
                                              const int* __restrict__ bbase,
                                              const float* __restrict__ dinv,
                                              const float* __restrict__ bias,
                                              float* __restrict__ out, int N) {
  __shared__ float acc[NPB * 64];
  int t = threadIdx.x;
  int b = blockIdx.x;
  int lane = t & 63, w = t >> 6;
  int node0 = b << BSH;
  int beg = bbase[b], end = bbase[b + 1];
  // seed with self-loop rows (H' pre-scaled)
  for (int dl = w; dl < NPB; dl += 4) {
    int v = node0 + dl;
    float hv = (v < N) ? __half2float(H[(size_t)v * 64 + lane]) : 0.f;
    acc[dl * 64 + ((lane & 1) << 5) + (lane >> 1)] = hv;
  }
  __syncthreads();
  int hl = lane & 31;
  for (int s0 = beg + w * 64; s0 < end; s0 += 256) {
    int navail = min(64, end - s0);
    int ev = (lane < navail) ? packed2[s0 + lane] : 0;
    int j = 0;
    for (; j + 4 <= navail; j += 4) {
      int ea0 = __shfl(ev, j + 0), ea1 = __shfl(ev, j + 1);
      int eb0 = __shfl(ev, j + 2), eb1 = __shfl(ev, j + 3);
      int mea = (lane < 32) ? ea0 : ea1;
      int meb = (lane < 32) ? eb0 : eb1;
      int sa = mea >> BSH, da = mea & BMSK;
      int sb = meb >> BSH, db = meb & BMSK;
      __half2 ha = *(const __half2*)(H + (size_t)sa * 64 + (hl << 1));
      __half2 hb = *(const __half2*)(H + (size_t)sb * 64 + (hl << 1));
      float2 fa = __half22float2(ha);
      float2 fb = __half22float2(hb);
      atomicAdd(&acc[da * 64 + hl], fa.x);
      atomicAdd(&acc[da * 64 + 32 + hl], fa.y);
      atomicAdd(&acc[db * 64 + hl], fb.x);
      atomicAdd(&acc[db * 64 + 32 + hl], fb.y);
    }
    for (; j + 2 <= navail; j += 2) {
      int e0 = __shfl(ev, j), e1 = __shfl(ev, j + 1);
      int me = (lane < 32) ? e0 : e1;
      int s = me >> BSH, dl = me & BMSK;
      __half2 hv = *(const __half2*)(H + (size_t)s * 64 + (hl << 1));
      float2 f = __half22float2(hv);
      atomicAdd(&acc[dl * 64 + hl], f.x);
      atomicAdd(&acc[dl * 64 + 32 + hl], f.y);
    }
    if (j < navail) {  // tail single edge: half wave
      int e0 = __shfl(ev, j);
      if (lane < 32) {
        int s = e0 >> BSH, dl = e0 & BMSK;
        __half2 hv = *(const __half2*)(H + (size_t)s * 64 + (hl << 1));
        float2 f = __half22float2(hv);
        atomicAdd(&acc[dl * 64 + hl], f.x);
        atomicAdd(&acc[dl * 64 + 32 + hl], f.y);
      }
    }
  }
  __syncthreads();
  // epilogue: * dinv[v] + bias (+relu), coalesced store
  for (int dl = w; dl < NPB; dl += 4) {
    int v = node0 + dl;
    if (v < N) {
      float r = acc[dl * 64 + ((lane & 1) << 5) + (lane >> 1)];
      r = fmaf(r, dinv[v], bias[lane]);
      if (RELU) r = fmaxf(r, 0.f);
      out[(size_t)v * 64 + lane] = r;
    }
  }
}

extern "C" void kernel_launch(void* const* d_in, const int* in_sizes, int n_in,
                              void* d_out, int out_size, void* d_ws, size_t ws_size,
                              hipStream_t stream) {
  const float* x  = (const float*)d_in[0];
  const float* W1 = (const float*)d_in[1];
  const float* b1 = (const float*)d_in[2];
  const float* W2 = (const float*)d_in[3];
  const float* b2 = (const float*)d_in[4];
  const int*   e0 = (const int*)d_in[5];
  const int*   e1 = (const int*)d_in[6];
  float* out = (float*)d_out;

  const int N = in_sizes[0] / 64;      // 100000
  const int E = in_sizes[5] / 2;       // 3200000
  const int B = (N + NPB - 1) / NPB;   // 782
  const int nchunk = (E + CHUNK - 1) / CHUNK;  // 782
  const int* src0 = e0;     const int* dst0 = e0 + E;
  const int* src1 = e1;     const int* dst1 = e1 + E;

  char* w = (char*)d_ws;
  size_t o = 0;
  auto carve = [&](size_t bytes) -> void* {
    void* p = w + o;
    o = (o + bytes + 255) & ~(size_t)255;
    return p;
  };
  int* btot12 = (int*)carve((size_t)2 * MAXB * 4);  // zero-init
  int* btot1 = btot12;
  int* btot2 = btot12 + MAXB;
  int* bbase = (int*)carve((MAXB + 1) * 4);
  int* runoff = (int*)carve((size_t)MAXCH * ROST * 4);        // shared
  int* runoffT = (int*)carve((size_t)(MAXB + 1) * MAXCH * 4); // shared
  float* dinv = (float*)carve((size_t)N * 4);      // shared (serialized)
  int* packed = (int*)carve((size_t)nchunk * CHUNK * 4);   // shared
  int* packed2 = (int*)carve((size_t)E * 4);       // shared (serialized)
  __half* H = (__half*)carve((size_t)N * 64 * 2);

  const dim3 tgrid((B + 1 + 31) / 32, (nchunk + 31) / 32);

  hipMemsetAsync(btot12, 0, (size_t)2 * MAXB * 4, stream);

  // layer 1
  k_scatter<<<nchunk, 256, 0, stream>>>(src0, dst0, runoff, btot1, packed, E, B);
  k_btot<<<1, 1024, 0, stream>>>(btot1, bbase, B, E);
  k_transpose<<<tgrid, 256, 0, stream>>>(runoff, runoffT, nchunk, B + 1);
  k_bfin2<<<B, 256, 0, stream>>>(packed, runoffT, bbase, dinv, packed2, N, B, nchunk);
  k_gemm64<<<2048, 256, 0, stream>>>(x, W1, dinv, H, N);
  k_aggp<true><<<B, 256, 0, stream>>>(H, packed2, bbase, dinv, b1, out, N);

  // layer 2 (all scratch reused; stream order serializes)
  k_scatter<<<nchunk, 256, 0, stream>>>(src1, dst1, runoff, btot2, packed, E, B);
  k_btot<<<1, 1024, 0, stream>>>(btot2, bbase, B, E);
  k_transpose<<<tgrid, 256, 0, stream>>>(runoff, runoffT, nchunk, B + 1);
  k_bfin2<<<B, 256, 0, stream>>>(packed, runoffT, bbase, dinv, packed2, N, B, nchunk);
  k_gemm64<<<2048, 256, 0, stream>>>(out, W2, dinv, H, N);
  k_aggp<false><<<B, 256, 0, stream>>>(H, packed2, bbase, dinv, b2, out, N);
}

// Round 8
// 535.625 us; speedup vs baseline: 5.9213x; 5.9213x over previous
//
#include <hip/hip_runtime.h>
#include <hip/hip_fp16.h>

// 2-layer GCN: out = gcn(relu(gcn(x,W1,b1,e0)), W2, b2, e1)
// R1-R5: CSR via LDS chunk-sort scatter (write-amp 1.0) + run tables +
//   transpose; H' = (XW)*dinv fp16; pull agg (wave/node).
// R7 post-mortem: push-mode agg (782 blocks) was latency-starved (23% occ,
//   VALUBusy 2.3%) -> 18x regression. Block count IS the latency-hiding
//   resource for random gathers; pull-mode with 25K blocks wins. Reverted.
// R8: (a) dual-edge pull agg: half-waves process even/odd edges, one
//   dword load fetches TWO fp16 rows (256B/instr), unroll 8 -> 2x fewer
//   gather instrs + 2x MLP. (b) bfin3: single-pass LDS bucket sort, csr
//   written coalesced (one scattered pass deleted). (c) gemm 8 rows/iter.

#define NPB   128
#define BSH   7
#define BMSK  127
#define MAXB  1024          // >= B = ceil(100000/128) = 782
#define ROST  (MAXB + 1)    // runoff row stride
#define CHUNK 4096
#define MAXCH 1024          // >= nchunk = ceil(E/CHUNK) = 782
#define BCAP  5120          // bucket stage cap (mean 4096, sd 64 -> +16sd)

// Sort chunk k by dst-bucket entirely in LDS; write packed[] coalesced.
__global__ __launch_bounds__(256) void k_scatter(const int* __restrict__ src,
                                                 const int* __restrict__ dst,
                                                 int* __restrict__ runoff,
                                                 int* __restrict__ btot,
                                                 int* __restrict__ packed,
                                                 int E, int B) {
  __shared__ int stage[CHUNK];
  __shared__ int sorted[CHUNK];
  __shared__ unsigned short bkt[CHUNK];
  __shared__ int hist[MAXB];
  __shared__ int wsum[4];
  int t = threadIdx.x;
  int k = blockIdx.x;
  int e0 = k * CHUNK;
  int cnt = min(CHUNK, E - e0);
  for (int b = t; b < B; b += 256) hist[b] = 0;
  __syncthreads();
  if (cnt == CHUNK) {
#pragma unroll
    for (int r = 0; r < 16; r += 4) {
      int i0 = (r + 0) * 256 + t, i1 = (r + 1) * 256 + t;
      int i2 = (r + 2) * 256 + t, i3 = (r + 3) * 256 + t;
      int d0 = dst[e0 + i0], d1 = dst[e0 + i1];
      int d2 = dst[e0 + i2], d3 = dst[e0 + i3];
      int s0 = src[e0 + i0], s1 = src[e0 + i1];
      int s2 = src[e0 + i2], s3 = src[e0 + i3];
      stage[i0] = (s0 << BSH) | (d0 & BMSK); bkt[i0] = (unsigned short)(d0 >> BSH);
      stage[i1] = (s1 << BSH) | (d1 & BMSK); bkt[i1] = (unsigned short)(d1 >> BSH);
      stage[i2] = (s2 << BSH) | (d2 & BMSK); bkt[i2] = (unsigned short)(d2 >> BSH);
      stage[i3] = (s3 << BSH) | (d3 & BMSK); bkt[i3] = (unsigned short)(d3 >> BSH);
      atomicAdd(&hist[d0 >> BSH], 1);
      atomicAdd(&hist[d1 >> BSH], 1);
      atomicAdd(&hist[d2 >> BSH], 1);
      atomicAdd(&hist[d3 >> BSH], 1);
    }
  } else {
    for (int i = t; i < cnt; i += 256) {
      int d = dst[e0 + i], s = src[e0 + i];
      stage[i] = (s << BSH) | (d & BMSK);
      bkt[i] = (unsigned short)(d >> BSH);
      atomicAdd(&hist[d >> BSH], 1);
    }
  }
  __syncthreads();
  int i0 = t * 4;
  int v0 = (i0 + 0 < B) ? hist[i0 + 0] : 0;
  int v1 = (i0 + 1 < B) ? hist[i0 + 1] : 0;
  int v2 = (i0 + 2 < B) ? hist[i0 + 2] : 0;
  int v3 = (i0 + 3 < B) ? hist[i0 + 3] : 0;
  if (v0) atomicAdd(&btot[i0 + 0], v0);
  if (v1) atomicAdd(&btot[i0 + 1], v1);
  if (v2) atomicAdd(&btot[i0 + 2], v2);
  if (v3) atomicAdd(&btot[i0 + 3], v3);
  int tsum = v0 + v1 + v2 + v3;
  int lane = t & 63, wid = t >> 6;
  int x = tsum;
#pragma unroll
  for (int d = 1; d < 64; d <<= 1) {
    int y = __shfl_up(x, d, 64);
    if (lane >= d) x += y;
  }
  if (lane == 63) wsum[wid] = x;
  __syncthreads();
  int wofs = 0;
  for (int ww = 0; ww < wid; ++ww) wofs += wsum[ww];
  int excl = wofs + x - tsum;
  hist[i0 + 0] = excl;
  hist[i0 + 1] = excl + v0;
  hist[i0 + 2] = excl + v0 + v1;
  hist[i0 + 3] = excl + v0 + v1 + v2;
  __syncthreads();
  int* row = runoff + (size_t)k * ROST;
  for (int b = t; b < B; b += 256) row[b] = hist[b];
  if (t == 0) row[B] = cnt;
  __syncthreads();
  for (int i = t; i < cnt; i += 256) {
    int pos = atomicAdd(&hist[bkt[i]], 1);
    sorted[pos] = stage[i];
  }
  __syncthreads();
  for (int i = t; i < cnt; i += 256) packed[e0 + i] = sorted[i];
}

// Exclusive scan of bucket totals -> bbase[0..B], bbase[B]=E. One block.
__global__ __launch_bounds__(1024) void k_btot(const int* __restrict__ btot,
                                               int* __restrict__ bbase,
                                               int B, int E) {
  __shared__ int wsum[16];
  int t = threadIdx.x;
  int c = (t < B) ? btot[t] : 0;
  int lane = t & 63, wid = t >> 6;
  int x = c;
#pragma unroll
  for (int d = 1; d < 64; d <<= 1) {
    int y = __shfl_up(x, d, 64);
    if (lane >= d) x += y;
  }
  if (lane == 63) wsum[wid] = x;
  __syncthreads();
  int wofs = 0;
  for (int ww = 0; ww < wid; ++ww) wofs += wsum[ww];
  if (t < B) bbase[t] = wofs + x - c;
  if (t == 0) bbase[B] = E;
}

// Tiled transpose: AT[b][k] = A[k][b].
__global__ __launch_bounds__(256) void k_transpose(const int* __restrict__ A,
                                                   int* __restrict__ AT,
                                                   int rows, int cols) {
  __shared__ int tile[32][33];
  int bx = blockIdx.x * 32;
  int by = blockIdx.y * 32;
  int tx = threadIdx.x & 31, ty = threadIdx.x >> 5;
#pragma unroll
  for (int q = 0; q < 4; ++q) {
    int r = by + ty + q * 8, c = bx + tx;
    if (r < rows && c < cols) tile[ty + q * 8][tx] = A[(size_t)r * ROST + c];
  }
  __syncthreads();
#pragma unroll
  for (int q = 0; q < 4; ++q) {
    int c = bx + ty + q * 8;
    int r = by + tx;
    if (c < cols && r < rows) AT[(size_t)c * MAXCH + r] = tile[tx][ty + q * 8];
  }
}

// Per-bucket finalize, single pass: stage runs in LDS -> count -> scan ->
// off/dinv -> LDS node-scatter -> coalesced csr writeout.
// Fallback (bucket > BCAP, ~never): old two-pass global path.
__global__ __launch_bounds__(256) void k_bfin3(const int* __restrict__ packed,
                                               const int* __restrict__ runoffT,
                                               const int* __restrict__ bbase,
                                               int* __restrict__ off,
                                               float* __restrict__ dinv,
                                               int* __restrict__ csr,
                                               int N, int B, int nchunk) {
  __shared__ int rs[MAXCH];
  __shared__ unsigned short rl[MAXCH];
  __shared__ int pref[MAXCH];
  __shared__ int stage[BCAP];
  __shared__ int sortedL[BCAP];
  __shared__ int cntL[NPB];
  __shared__ int curL[NPB];
  __shared__ int wsum[4];
  int t = threadIdx.x;
  int b = blockIdx.x;
  for (int k = t; k < nchunk; k += 256) {
    int s = runoffT[(size_t)b * MAXCH + k];
    int e = runoffT[(size_t)(b + 1) * MAXCH + k];
    rs[k] = k * CHUNK + s;
    rl[k] = (unsigned short)(e - s);
  }
  if (t < NPB) cntL[t] = 0;
  __syncthreads();
  // scan run lengths -> pref (256 threads x 4 = 1024 >= nchunk)
  int i0 = t * 4;
  int v0 = (i0 + 0 < nchunk) ? rl[i0 + 0] : 0;
  int v1 = (i0 + 1 < nchunk) ? rl[i0 + 1] : 0;
  int v2 = (i0 + 2 < nchunk) ? rl[i0 + 2] : 0;
  int v3 = (i0 + 3 < nchunk) ? rl[i0 + 3] : 0;
  int tsum = v0 + v1 + v2 + v3;
  int lane = t & 63, w = t >> 6;
  int x = tsum;
#pragma unroll
  for (int d = 1; d < 64; d <<= 1) {
    int y = __shfl_up(x, d, 64);
    if (lane >= d) x += y;
  }
  if (lane == 63) wsum[w] = x;
  __syncthreads();
  int wofs = 0;
  for (int ww = 0; ww < w; ++ww) wofs += wsum[ww];
  int excl = wofs + x - tsum;
  pref[i0 + 0] = excl;
  pref[i0 + 1] = excl + v0;
  pref[i0 + 2] = excl + v0 + v1;
  pref[i0 + 3] = excl + v0 + v1 + v2;
  __syncthreads();
  int wbase = bbase[b];
  int total = bbase[b + 1] - wbase;
  bool inLDS = (total <= BCAP);
  if (inLDS) {
    // stage runs into LDS, then count from LDS
    for (int k = t; k < nchunk; k += 256) {
      int base = rs[k], len = rl[k], o = pref[k];
      for (int j = 0; j < len; ++j) stage[o + j] = packed[base + j];
    }
    __syncthreads();
    for (int i = t; i < total; i += 256)
      atomicAdd(&cntL[stage[i] & BMSK], 1);
  } else {
    for (int k = t; k < nchunk; k += 256) {
      int base = rs[k], len = rl[k];
      for (int j = 0; j < len; ++j)
        atomicAdd(&cntL[packed[base + j] & BMSK], 1);
    }
  }
  __syncthreads();
  // scan 128 node counts
  int c = (t < NPB) ? cntL[t] : 0;
  x = c;
#pragma unroll
  for (int d = 1; d < 64; d <<= 1) {
    int y = __shfl_up(x, d, 64);
    if (lane >= d) x += y;
  }
  if (lane == 63) wsum[w] = x;
  __syncthreads();
  wofs = 0;
  for (int ww = 0; ww < w; ++ww) wofs += wsum[ww];
  int nexcl = wofs + x - c;  // bucket-local exclusive prefix
  int v = (b << BSH) + t;
  if (t < NPB && v < N) {
    off[v] = wbase + nexcl;
    dinv[v] = rsqrtf((float)(c + 1));  // +1 self-loop
  }
  if (t < NPB) curL[t] = inLDS ? nexcl : (wbase + nexcl);
  if (b == B - 1 && t == 0) off[N] = bbase[B];
  __syncthreads();
  if (inLDS) {
    for (int i = t; i < total; i += 256) {
      int e = stage[i];
      int p = atomicAdd(&curL[e & BMSK], 1);
      sortedL[p] = e >> BSH;
    }
    __syncthreads();
    for (int i = t; i < total; i += 256) csr[wbase + i] = sortedL[i];
  } else {
    for (int k = t; k < nchunk; k += 256) {
      int base = rs[k], len = rl[k];
      for (int j = 0; j < len; ++j) {
        int e = packed[base + j];
        int p = atomicAdd(&curL[e & BMSK], 1);
        csr[p] = e >> BSH;
      }
    }
  }
}

// H'[v] = fp16((X @ W)[v] * dinv[v]).  W (16KB) in LDS; 8 nodes/block-iter.
__global__ __launch_bounds__(256) void k_gemm64(const float* __restrict__ X,
                                                const float* __restrict__ W,
                                                const float* __restrict__ dinv,
                                                __half* __restrict__ H, int N) {
  __shared__ float Wl[4096];
  __shared__ float Xl[512];
  for (int t = threadIdx.x; t < 4096; t += 256) Wl[t] = W[t];
  int j = threadIdx.x & 63;
  int nl = threadIdx.x >> 6;
  for (int base = blockIdx.x * 8; base < N; base += gridDim.x * 8) {
    __syncthreads();
    int gi = base * 64 + threadIdx.x;
    Xl[threadIdx.x] = (gi < N * 64) ? X[gi] : 0.f;
    int gi2 = gi + 256;
    Xl[threadIdx.x + 256] = (gi2 < N * 64) ? X[gi2] : 0.f;
    __syncthreads();
#pragma unroll
    for (int q = 0; q < 2; ++q) {
      int v = base + nl + q * 4;
      if (v < N) {
        const float* xr = &Xl[(nl + q * 4) * 64];
        float acc = 0.f;
#pragma unroll
        for (int k = 0; k < 64; k += 4) {
          acc = fmaf(xr[k + 0], Wl[(k + 0) * 64 + j], acc);
          acc = fmaf(xr[k + 1], Wl[(k + 1) * 64 + j], acc);
          acc = fmaf(xr[k + 2], Wl[(k + 2) * 64 + j], acc);
          acc = fmaf(xr[k + 3], Wl[(k + 3) * 64 + j], acc);
        }
        H[(size_t)v * 64 + j] = __float2half_rn(acc * dinv[v]);
      }
    }
  }
}

// Pull aggregation, dual-edge: one wave per node. Lane L owns features
// (2*(L&31), 2*(L&31)+1); half-wave 0 processes even edges, half 1 odd.
// One dword load fetches TWO fp16 rows per instr (256B); unroll 8.
// Halves merged via shfl_xor(32); float2 epilogue store.
template <bool RELU>
__global__ __launch_bounds__(256) void k_agg(const __half* __restrict__ H,
                                             const int* __restrict__ csr,
                                             const int* __restrict__ off,
                                             const float* __restrict__ dinv,
                                             const float* __restrict__ bias,
                                             float* __restrict__ out, int N) {
  int wid = (blockIdx.x * blockDim.x + threadIdx.x) >> 6;
  int lane = threadIdx.x & 63;
  if (wid >= N) return;
  int hl = lane & 31;
  int half = lane >> 5;
  int beg = off[wid];
  int num = off[wid + 1] - beg;
  const __half2* Hp = (const __half2*)H;
  // seed self-loop once (half 0 only); H' is pre-scaled by dinv[src]
  float2 fs = __half22float2(Hp[(size_t)wid * 32 + hl]);
  float2 acc = half ? make_float2(0.f, 0.f) : fs;
  for (int base = 0; base < num; base += 64) {
    int navail = min(64, num - base);
    int sv = (base + lane < num) ? csr[beg + base + lane] : 0;
    int npair = navail >> 1;
    int i = 0;
    for (; i + 8 <= npair; i += 8) {
      int e0 = __shfl(sv, 2 * (i + 0) + half), e1 = __shfl(sv, 2 * (i + 1) + half);
      int e2 = __shfl(sv, 2 * (i + 2) + half), e3 = __shfl(sv, 2 * (i + 3) + half);
      int e4 = __shfl(sv, 2 * (i + 4) + half), e5 = __shfl(sv, 2 * (i + 5) + half);
      int e6 = __shfl(sv, 2 * (i + 6) + half), e7 = __shfl(sv, 2 * (i + 7) + half);
      float2 f0 = __half22float2(Hp[(size_t)e0 * 32 + hl]);
      float2 f1 = __half22float2(Hp[(size_t)e1 * 32 + hl]);
      float2 f2 = __half22float2(Hp[(size_t)e2 * 32 + hl]);
      float2 f3 = __half22float2(Hp[(size_t)e3 * 32 + hl]);
      float2 f4 = __half22float2(Hp[(size_t)e4 * 32 + hl]);
      float2 f5 = __half22float2(Hp[(size_t)e5 * 32 + hl]);
      float2 f6 = __half22float2(Hp[(size_t)e6 * 32 + hl]);
      float2 f7 = __half22float2(Hp[(size_t)e7 * 32 + hl]);
      acc.x += f0.x + f1.x + f2.x + f3.x;
      acc.y += f0.y + f1.y + f2.y + f3.y;
      acc.x += f4.x + f5.x + f6.x + f7.x;
      acc.y += f4.y + f5.y + f6.y + f7.y;
    }
    for (; i < npair; ++i) {
      int e = __shfl(sv, 2 * i + half);
      float2 f = __half22float2(Hp[(size_t)e * 32 + hl]);
      acc.x += f.x; acc.y += f.y;
    }
    if (navail & 1) {  // odd tail: half 0 takes the last edge
      int e = __shfl(sv, navail - 1);
      if (!half) {
        float2 f = __half22float2(Hp[(size_t)e * 32 + hl]);
        acc.x += f.x; acc.y += f.y;
      }
    }
  }
  acc.x += __shfl_xor(acc.x, 32);
  acc.y += __shfl_xor(acc.y, 32);
  if (!half) {
    float dv = dinv[wid];
    float2 bb = ((const float2*)bias)[hl];
    float2 r;
    r.x = fmaf(acc.x, dv, bb.x);
    r.y = fmaf(acc.y, dv, bb.y);
    if (RELU) { r.x = fmaxf(r.x, 0.f); r.y = fmaxf(r.y, 0.f); }
    ((float2*)(out + (size_t)wid * 64))[hl] = r;
  }
}

extern "C" void kernel_launch(void* const* d_in, const int* in_sizes, int n_in,
                              void* d_out, int out_size, void* d_ws, size_t ws_size,
                              hipStream_t stream) {
  const float* x  = (const float*)d_in[0];
  const float* W1 = (const float*)d_in[1];
  const float* b1 = (const float*)d_in[2];
  const float* W2 = (const float*)d_in[3];
  const float* b2 = (const float*)d_in[4];
  const int*   e0 = (const int*)d_in[5];
  const int*   e1 = (const int*)d_in[6];
  float* out = (float*)d_out;

  const int N = in_sizes[0] / 64;      // 100000
  const int E = in_sizes[5] / 2;       // 3200000
  const int B = (N + NPB - 1) / NPB;   // 782
  const int nchunk = (E + CHUNK - 1) / CHUNK;  // 782
  const int* src0 = e0;     const int* dst0 = e0 + E;
  const int* src1 = e1;     const int* dst1 = e1 + E;

  char* w = (char*)d_ws;
  size_t o = 0;
  auto carve = [&](size_t bytes) -> void* {
    void* p = w + o;
    o = (o + bytes + 255) & ~(size_t)255;
    return p;
  };
  int* btot12 = (int*)carve((size_t)2 * MAXB * 4);  // zero-init
  int* btot1 = btot12;
  int* btot2 = btot12 + MAXB;
  int* bbase = (int*)carve((MAXB + 1) * 4);
  int* runoff = (int*)carve((size_t)MAXCH * ROST * 4);        // shared
  int* runoffT = (int*)carve((size_t)(MAXB + 1) * MAXCH * 4); // shared
  int* off = (int*)carve((size_t)(N + 1) * 4);     // shared (serialized)
  float* dinv = (float*)carve((size_t)N * 4);      // shared (serialized)
  int* packed = (int*)carve((size_t)nchunk * CHUNK * 4);  // shared
  int* csr = (int*)carve((size_t)E * 4);           // shared (serialized)
  __half* H = (__half*)carve((size_t)N * 64 * 2);

  const int aggblk = (N * 64 + 255) / 256;  // 25000
  const dim3 tgrid((B + 1 + 31) / 32, (nchunk + 31) / 32);

  hipMemsetAsync(btot12, 0, (size_t)2 * MAXB * 4, stream);

  // layer 1
  k_scatter<<<nchunk, 256, 0, stream>>>(src0, dst0, runoff, btot1, packed, E, B);
  k_btot<<<1, 1024, 0, stream>>>(btot1, bbase, B, E);
  k_transpose<<<tgrid, 256, 0, stream>>>(runoff, runoffT, nchunk, B + 1);
  k_bfin3<<<B, 256, 0, stream>>>(packed, runoffT, bbase, off, dinv, csr, N, B, nchunk);
  k_gemm64<<<2048, 256, 0, stream>>>(x, W1, dinv, H, N);
  k_agg<true><<<aggblk, 256, 0, stream>>>(H, csr, off, dinv, b1, out, N);

  // layer 2 (all scratch reused; stream order serializes)
  k_scatter<<<nchunk, 256, 0, stream>>>(src1, dst1, runoff, btot2, packed, E, B);
  k_btot<<<1, 1024, 0, stream>>>(btot2, bbase, B, E);
  k_transpose<<<tgrid, 256, 0, stream>>>(runoff, runoffT, nchunk, B + 1);
  k_bfin3<<<B, 256, 0, stream>>>(packed, runoffT, bbase, off, dinv, csr, N, B, nchunk);
  k_gemm64<<<2048, 256, 0, stream>>>(out, W2, dinv, H, N);
  k_agg<false><<<aggblk, 256, 0, stream>>>(H, csr, off, dinv, b2, out, N);
}

// Round 9
// 527.025 us; speedup vs baseline: 6.0180x; 1.0163x over previous
//
#include <hip/hip_runtime.h>
#include <hip/hip_fp16.h>

// 2-layer GCN: out = gcn(relu(gcn(x,W1,b1,e0)), W2, b2, e1)
// R1-R6: CSR via LDS chunk-sort scatter + run tables + transpose; H' =
//   (XW)*dinv fp16; pull agg. R7: push-agg failed (block count IS the
//   latency-hiding resource for random gathers) -> reverted.
// R8: dual-edge pull agg (2 fp16 rows / dword load), single-pass bfin3,
//   gemm 8 rows/iter -> 535us. Scatter now the leader: 23.6% occ,
//   VALUBusy 2.8% -> latency-starved at 3 blocks/CU (45.5KB LDS).
// R9: register-held scatter. stage[]/bkt[] (24KB LDS) existed only to
//   carry edge data between passes -- hold pk[16]/bk[16] in VGPRs instead.
//   4x int4 loads (blocked per-thread layout), LDS 45.5->20.3KB,
//   ~5-7 blocks/CU. Everything else identical to benched R8.

#define NPB   128
#define BSH   7
#define BMSK  127
#define MAXB  1024          // >= B = ceil(100000/128) = 782
#define ROST  (MAXB + 1)    // runoff row stride
#define CHUNK 4096
#define EPTH  16            // edges per thread = CHUNK/256
#define MAXCH 1024          // >= nchunk = ceil(E/CHUNK) = 782
#define BCAP  5120          // bucket stage cap (mean 4096, sd 64 -> +16sd)

// Sort chunk k by dst-bucket; edge data held in REGISTERS between passes.
__global__ __launch_bounds__(256) void k_scatter(const int* __restrict__ src,
                                                 const int* __restrict__ dst,
                                                 int* __restrict__ runoff,
                                                 int* __restrict__ btot,
                                                 int* __restrict__ packed,
                                                 int E, int B) {
  __shared__ int sorted[CHUNK];
  __shared__ int hist[MAXB];
  __shared__ int wsum[4];
  int t = threadIdx.x;
  int k = blockIdx.x;
  int e0 = k * CHUNK;
  int cnt = min(CHUNK, E - e0);
  for (int b = t; b < B; b += 256) hist[b] = 0;
  __syncthreads();
  int pk[EPTH];
  int bk[EPTH];
  int base = t * EPTH;          // this thread's 16 consecutive edges
  int nloc = min(EPTH, max(0, cnt - base));
  if (cnt == CHUNK) {
    const int4* s4 = (const int4*)(src + e0 + base);
    const int4* d4 = (const int4*)(dst + e0 + base);
#pragma unroll
    for (int g = 0; g < 4; ++g) {
      int4 sv = s4[g];
      int4 dv = d4[g];
      pk[4 * g + 0] = (sv.x << BSH) | (dv.x & BMSK); bk[4 * g + 0] = dv.x >> BSH;
      pk[4 * g + 1] = (sv.y << BSH) | (dv.y & BMSK); bk[4 * g + 1] = dv.y >> BSH;
      pk[4 * g + 2] = (sv.z << BSH) | (dv.z & BMSK); bk[4 * g + 2] = dv.z >> BSH;
      pk[4 * g + 3] = (sv.w << BSH) | (dv.w & BMSK); bk[4 * g + 3] = dv.w >> BSH;
      atomicAdd(&hist[bk[4 * g + 0]], 1);
      atomicAdd(&hist[bk[4 * g + 1]], 1);
      atomicAdd(&hist[bk[4 * g + 2]], 1);
      atomicAdd(&hist[bk[4 * g + 3]], 1);
    }
  } else {
    for (int q = 0; q < nloc; ++q) {
      int d = dst[e0 + base + q], s = src[e0 + base + q];
      pk[q] = (s << BSH) | (d & BMSK);
      bk[q] = d >> BSH;
      atomicAdd(&hist[bk[q]], 1);
    }
  }
  __syncthreads();
  // block scan over B bins (256 threads x 4)
  int i0 = t * 4;
  int v0 = (i0 + 0 < B) ? hist[i0 + 0] : 0;
  int v1 = (i0 + 1 < B) ? hist[i0 + 1] : 0;
  int v2 = (i0 + 2 < B) ? hist[i0 + 2] : 0;
  int v3 = (i0 + 3 < B) ? hist[i0 + 3] : 0;
  if (v0) atomicAdd(&btot[i0 + 0], v0);
  if (v1) atomicAdd(&btot[i0 + 1], v1);
  if (v2) atomicAdd(&btot[i0 + 2], v2);
  if (v3) atomicAdd(&btot[i0 + 3], v3);
  int tsum = v0 + v1 + v2 + v3;
  int lane = t & 63, wid = t >> 6;
  int x = tsum;
#pragma unroll
  for (int d = 1; d < 64; d <<= 1) {
    int y = __shfl_up(x, d, 64);
    if (lane >= d) x += y;
  }
  if (lane == 63) wsum[wid] = x;
  __syncthreads();
  int wofs = 0;
  for (int ww = 0; ww < wid; ++ww) wofs += wsum[ww];
  int excl = wofs + x - tsum;
  hist[i0 + 0] = excl;
  hist[i0 + 1] = excl + v0;
  hist[i0 + 2] = excl + v0 + v1;
  hist[i0 + 3] = excl + v0 + v1 + v2;
  __syncthreads();
  // write run-offset row BEFORE cursors get bumped
  int* row = runoff + (size_t)k * ROST;
  for (int b = t; b < B; b += 256) row[b] = hist[b];
  if (t == 0) row[B] = cnt;
  __syncthreads();
  // pass 2: registers -> sorted[] via LDS cursors
#pragma unroll
  for (int q = 0; q < EPTH; ++q) {
    if (q < nloc) {
      int pos = atomicAdd(&hist[bk[q]], 1);
      sorted[pos] = pk[q];
    }
  }
  __syncthreads();
  // pass 3: coalesced sequential writeout (int4)
  if (cnt == CHUNK) {
    int4* po = (int4*)(packed + e0 + base);
    const int4* so = (const int4*)(sorted + base);
#pragma unroll
    for (int g = 0; g < 4; ++g) po[g] = so[g];
  } else {
    for (int i = t; i < cnt; i += 256) packed[e0 + i] = sorted[i];
  }
}

// Exclusive scan of bucket totals -> bbase[0..B], bbase[B]=E. One block.
__global__ __launch_bounds__(1024) void k_btot(const int* __restrict__ btot,
                                               int* __restrict__ bbase,
                                               int B, int E) {
  __shared__ int wsum[16];
  int t = threadIdx.x;
  int c = (t < B) ? btot[t] : 0;
  int lane = t & 63, wid = t >> 6;
  int x = c;
#pragma unroll
  for (int d = 1; d < 64; d <<= 1) {
    int y = __shfl_up(x, d, 64);
    if (lane >= d) x += y;
  }
  if (lane == 63) wsum[wid] = x;
  __syncthreads();
  int wofs = 0;
  for (int ww = 0; ww < wid; ++ww) wofs += wsum[ww];
  if (t < B) bbase[t] = wofs + x - c;
  if (t == 0) bbase[B] = E;
}

// Tiled transpose: AT[b][k] = A[k][b].
__global__ __launch_bounds__(256) void k_transpose(const int* __restrict__ A,
                                                   int* __restrict__ AT,
                                                   int rows, int cols) {
  __shared__ int tile[32][33];
  int bx = blockIdx.x * 32;
  int by = blockIdx.y * 32;
  int tx = threadIdx.x & 31, ty = threadIdx.x >> 5;
#pragma unroll
  for (int q = 0; q < 4; ++q) {
    int r = by + ty + q * 8, c = bx + tx;
    if (r < rows && c < cols) tile[ty + q * 8][tx] = A[(size_t)r * ROST + c];
  }
  __syncthreads();
#pragma unroll
  for (int q = 0; q < 4; ++q) {
    int c = bx + ty + q * 8;
    int r = by + tx;
    if (c < cols && r < rows) AT[(size_t)c * MAXCH + r] = tile[tx][ty + q * 8];
  }
}

// Per-bucket finalize, single pass: stage runs in LDS -> count -> scan ->
// off/dinv -> LDS node-scatter -> coalesced csr writeout.
__global__ __launch_bounds__(256) void k_bfin3(const int* __restrict__ packed,
                                               const int* __restrict__ runoffT,
                                               const int* __restrict__ bbase,
                                               int* __restrict__ off,
                                               float* __restrict__ dinv,
                                               int* __restrict__ csr,
                                               int N, int B, int nchunk) {
  __shared__ int rs[MAXCH];
  __shared__ unsigned short rl[MAXCH];
  __shared__ int pref[MAXCH];
  __shared__ int stage[BCAP];
  __shared__ int sortedL[BCAP];
  __shared__ int cntL[NPB];
  __shared__ int curL[NPB];
  __shared__ int wsum[4];
  int t = threadIdx.x;
  int b = blockIdx.x;
  for (int k = t; k < nchunk; k += 256) {
    int s = runoffT[(size_t)b * MAXCH + k];
    int e = runoffT[(size_t)(b + 1) * MAXCH + k];
    rs[k] = k * CHUNK + s;
    rl[k] = (unsigned short)(e - s);
  }
  if (t < NPB) cntL[t] = 0;
  __syncthreads();
  int i0 = t * 4;
  int v0 = (i0 + 0 < nchunk) ? rl[i0 + 0] : 0;
  int v1 = (i0 + 1 < nchunk) ? rl[i0 + 1] : 0;
  int v2 = (i0 + 2 < nchunk) ? rl[i0 + 2] : 0;
  int v3 = (i0 + 3 < nchunk) ? rl[i0 + 3] : 0;
  int tsum = v0 + v1 + v2 + v3;
  int lane = t & 63, w = t >> 6;
  int x = tsum;
#pragma unroll
  for (int d = 1; d < 64; d <<= 1) {
    int y = __shfl_up(x, d, 64);
    if (lane >= d) x += y;
  }
  if (lane == 63) wsum[w] = x;
  __syncthreads();
  int wofs = 0;
  for (int ww = 0; ww < w; ++ww) wofs += wsum[ww];
  int excl = wofs + x - tsum;
  pref[i0 + 0] = excl;
  pref[i0 + 1] = excl + v0;
  pref[i0 + 2] = excl + v0 + v1;
  pref[i0 + 3] = excl + v0 + v1 + v2;
  __syncthreads();
  int wbase = bbase[b];
  int total = bbase[b + 1] - wbase;
  bool inLDS = (total <= BCAP);
  if (inLDS) {
    for (int k = t; k < nchunk; k += 256) {
      int base = rs[k], len = rl[k], o = pref[k];
      for (int j = 0; j < len; ++j) stage[o + j] = packed[base + j];
    }
    __syncthreads();
    for (int i = t; i < total; i += 256)
      atomicAdd(&cntL[stage[i] & BMSK], 1);
  } else {
    for (int k = t; k < nchunk; k += 256) {
      int base = rs[k], len = rl[k];
      for (int j = 0; j < len; ++j)
        atomicAdd(&cntL[packed[base + j] & BMSK], 1);
    }
  }
  __syncthreads();
  int c = (t < NPB) ? cntL[t] : 0;
  x = c;
#pragma unroll
  for (int d = 1; d < 64; d <<= 1) {
    int y = __shfl_up(x, d, 64);
    if (lane >= d) x += y;
  }
  if (lane == 63) wsum[w] = x;
  __syncthreads();
  wofs = 0;
  for (int ww = 0; ww < w; ++ww) wofs += wsum[ww];
  int nexcl = wofs + x - c;
  int v = (b << BSH) + t;
  if (t < NPB && v < N) {
    off[v] = wbase + nexcl;
    dinv[v] = rsqrtf((float)(c + 1));  // +1 self-loop
  }
  if (t < NPB) curL[t] = inLDS ? nexcl : (wbase + nexcl);
  if (b == B - 1 && t == 0) off[N] = bbase[B];
  __syncthreads();
  if (inLDS) {
    for (int i = t; i < total; i += 256) {
      int e = stage[i];
      int p = atomicAdd(&curL[e & BMSK], 1);
      sortedL[p] = e >> BSH;
    }
    __syncthreads();
    for (int i = t; i < total; i += 256) csr[wbase + i] = sortedL[i];
  } else {
    for (int k = t; k < nchunk; k += 256) {
      int base = rs[k], len = rl[k];
      for (int j = 0; j < len; ++j) {
        int e = packed[base + j];
        int p = atomicAdd(&curL[e & BMSK], 1);
        csr[p] = e >> BSH;
      }
    }
  }
}

// H'[v] = fp16((X @ W)[v] * dinv[v]).  W (16KB) in LDS; 8 nodes/block-iter.
__global__ __launch_bounds__(256) void k_gemm64(const float* __restrict__ X,
                                                const float* __restrict__ W,
                                                const float* __restrict__ dinv,
                                                __half* __restrict__ H, int N) {
  __shared__ float Wl[4096];
  __shared__ float Xl[512];
  for (int t = threadIdx.x; t < 4096; t += 256) Wl[t] = W[t];
  int j = threadIdx.x & 63;
  int nl = threadIdx.x >> 6;
  for (int base = blockIdx.x * 8; base < N; base += gridDim.x * 8) {
    __syncthreads();
    int gi = base * 64 + threadIdx.x;
    Xl[threadIdx.x] = (gi < N * 64) ? X[gi] : 0.f;
    int gi2 = gi + 256;
    Xl[threadIdx.x + 256] = (gi2 < N * 64) ? X[gi2] : 0.f;
    __syncthreads();
#pragma unroll
    for (int q = 0; q < 2; ++q) {
      int v = base + nl + q * 4;
      if (v < N) {
        const float* xr = &Xl[(nl + q * 4) * 64];
        float acc = 0.f;
#pragma unroll
        for (int k = 0; k < 64; k += 4) {
          acc = fmaf(xr[k + 0], Wl[(k + 0) * 64 + j], acc);
          acc = fmaf(xr[k + 1], Wl[(k + 1) * 64 + j], acc);
          acc = fmaf(xr[k + 2], Wl[(k + 2) * 64 + j], acc);
          acc = fmaf(xr[k + 3], Wl[(k + 3) * 64 + j], acc);
        }
        H[(size_t)v * 64 + j] = __float2half_rn(acc * dinv[v]);
      }
    }
  }
}

// Pull aggregation, dual-edge (benched R8 version, unchanged).
template <bool RELU>
__global__ __launch_bounds__(256) void k_agg(const __half* __restrict__ H,
                                             const int* __restrict__ csr,
                                             const int* __restrict__ off,
                                             const float* __restrict__ dinv,
                                             const float* __restrict__ bias,
                                             float* __restrict__ out, int N) {
  int wid = (blockIdx.x * blockDim.x + threadIdx.x) >> 6;
  int lane = threadIdx.x & 63;
  if (wid >= N) return;
  int hl = lane & 31;
  int half = lane >> 5;
  int beg = off[wid];
  int num = off[wid + 1] - beg;
  const __half2* Hp = (const __half2*)H;
  float2 fs = __half22float2(Hp[(size_t)wid * 32 + hl]);
  float2 acc = half ? make_float2(0.f, 0.f) : fs;
  for (int base = 0; base < num; base += 64) {
    int navail = min(64, num - base);
    int sv = (base + lane < num) ? csr[beg + base + lane] : 0;
    int npair = navail >> 1;
    int i = 0;
    for (; i + 8 <= npair; i += 8) {
      int e0 = __shfl(sv, 2 * (i + 0) + half), e1 = __shfl(sv, 2 * (i + 1) + half);
      int e2 = __shfl(sv, 2 * (i + 2) + half), e3 = __shfl(sv, 2 * (i + 3) + half);
      int e4 = __shfl(sv, 2 * (i + 4) + half), e5 = __shfl(sv, 2 * (i + 5) + half);
      int e6 = __shfl(sv, 2 * (i + 6) + half), e7 = __shfl(sv, 2 * (i + 7) + half);
      float2 f0 = __half22float2(Hp[(size_t)e0 * 32 + hl]);
      float2 f1 = __half22float2(Hp[(size_t)e1 * 32 + hl]);
      float2 f2 = __half22float2(Hp[(size_t)e2 * 32 + hl]);
      float2 f3 = __half22float2(Hp[(size_t)e3 * 32 + hl]);
      float2 f4 = __half22float2(Hp[(size_t)e4 * 32 + hl]);
      float2 f5 = __half22float2(Hp[(size_t)e5 * 32 + hl]);
      float2 f6 = __half22float2(Hp[(size_t)e6 * 32 + hl]);
      float2 f7 = __half22float2(Hp[(size_t)e7 * 32 + hl]);
      acc.x += f0.x + f1.x + f2.x + f3.x;
      acc.y += f0.y + f1.y + f2.y + f3.y;
      acc.x += f4.x + f5.x + f6.x + f7.x;
      acc.y += f4.y + f5.y + f6.y + f7.y;
    }
    for (; i < npair; ++i) {
      int e = __shfl(sv, 2 * i + half);
      float2 f = __half22float2(Hp[(size_t)e * 32 + hl]);
      acc.x += f.x; acc.y += f.y;
    }
    if (navail & 1) {
      int e = __shfl(sv, navail - 1);
      if (!half) {
        float2 f = __half22float2(Hp[(size_t)e * 32 + hl]);
        acc.x += f.x; acc.y += f.y;
      }
    }
  }
  acc.x += __shfl_xor(acc.x, 32);
  acc.y += __shfl_xor(acc.y, 32);
  if (!half) {
    float dv = dinv[wid];
    float2 bb = ((const float2*)bias)[hl];
    float2 r;
    r.x = fmaf(acc.x, dv, bb.x);
    r.y = fmaf(acc.y, dv, bb.y);
    if (RELU) { r.x = fmaxf(r.x, 0.f); r.y = fmaxf(r.y, 0.f); }
    ((float2*)(out + (size_t)wid * 64))[hl] = r;
  }
}

extern "C" void kernel_launch(void* const* d_in, const int* in_sizes, int n_in,
                              void* d_out, int out_size, void* d_ws, size_t ws_size,
                              hipStream_t stream) {
  const float* x  = (const float*)d_in[0];
  const float* W1 = (const float*)d_in[1];
  const float* b1 = (const float*)d_in[2];
  const float* W2 = (const float*)d_in[3];
  const float* b2 = (const float*)d_in[4];
  const int*   e0 = (const int*)d_in[5];
  const int*   e1 = (const int*)d_in[6];
  float* out = (float*)d_out;

  const int N = in_sizes[0] / 64;      // 100000
  const int E = in_sizes[5] / 2;       // 3200000
  const int B = (N + NPB - 1) / NPB;   // 782
  const int nchunk = (E + CHUNK - 1) / CHUNK;  // 782
  const int* src0 = e0;     const int* dst0 = e0 + E;
  const int* src1 = e1;     const int* dst1 = e1 + E;

  char* w = (char*)d_ws;
  size_t o = 0;
  auto carve = [&](size_t bytes) -> void* {
    void* p = w + o;
    o = (o + bytes + 255) & ~(size_t)255;
    return p;
  };
  int* btot12 = (int*)carve((size_t)2 * MAXB * 4);  // zero-init
  int* btot1 = btot12;
  int* btot2 = btot12 + MAXB;
  int* bbase = (int*)carve((MAXB + 1) * 4);
  int* runoff = (int*)carve((size_t)MAXCH * ROST * 4);        // shared
  int* runoffT = (int*)carve((size_t)(MAXB + 1) * MAXCH * 4); // shared
  int* off = (int*)carve((size_t)(N + 1) * 4);     // shared (serialized)
  float* dinv = (float*)carve((size_t)N * 4);      // shared (serialized)
  int* packed = (int*)carve((size_t)nchunk * CHUNK * 4);  // shared
  int* csr = (int*)carve((size_t)E * 4);           // shared (serialized)
  __half* H = (__half*)carve((size_t)N * 64 * 2);

  const int aggblk = (N * 64 + 255) / 256;  // 25000
  const dim3 tgrid((B + 1 + 31) / 32, (nchunk + 31) / 32);

  hipMemsetAsync(btot12, 0, (size_t)2 * MAXB * 4, stream);

  // layer 1
  k_scatter<<<nchunk, 256, 0, stream>>>(src0, dst0, runoff, btot1, packed, E, B);
  k_btot<<<1, 1024, 0, stream>>>(btot1, bbase, B, E);
  k_transpose<<<tgrid, 256, 0, stream>>>(runoff, runoffT, nchunk, B + 1);
  k_bfin3<<<B, 256, 0, stream>>>(packed, runoffT, bbase, off, dinv, csr, N, B, nchunk);
  k_gemm64<<<2048, 256, 0, stream>>>(x, W1, dinv, H, N);
  k_agg<true><<<aggblk, 256, 0, stream>>>(H, csr, off, dinv, b1, out, N);

  // layer 2 (all scratch reused; stream order serializes)
  k_scatter<<<nchunk, 256, 0, stream>>>(src1, dst1, runoff, btot2, packed, E, B);
  k_btot<<<1, 1024, 0, stream>>>(btot2, bbase, B, E);
  k_transpose<<<tgrid, 256, 0, stream>>>(runoff, runoffT, nchunk, B + 1);
  k_bfin3<<<B, 256, 0, stream>>>(packed, runoffT, bbase, off, dinv, csr, N, B, nchunk);
  k_gemm64<<<2048, 256, 0, stream>>>(out, W2, dinv, H, N);
  k_agg<false><<<aggblk, 256, 0, stream>>>(H, csr, off, dinv, b2, out, N);
}

// Round 10
// 426.716 us; speedup vs baseline: 7.4326x; 1.2351x over previous
//
#include <hip/hip_runtime.h>
#include <hip/hip_fp16.h>

// 2-layer GCN: out = gcn(relu(gcn(x,W1,b1,e0)), W2, b2, e1)
// R1-R8: CSR via LDS chunk-sort scatter + run tables + transpose; H' =
//   (XW)*dinv fp16; dual-edge pull agg; single-pass bfin3. Push-agg (R7)
//   failed: block count IS the latency-hiding resource for random gathers.
// R9: register-held scatter (LDS 45.5->21KB) -> no change: 71us floor.
// R10: R8 vs R9 scatter identical at ~71us despite different structure ->
//   shared bottleneck = btot: ~780K device-scope atomicAdds into a 4KB
//   array (64 lines), serialized line-exclusive across 8 XCDs, drained by
//   vmcnt(0) before the barrier. Fix: ZERO global atomics -- bucket totals
//   recomputed from the run-offset table after transpose (k_bsum: wave per
//   bucket, coalesced column sum, plain stores).

#define NPB   128
#define BSH   7
#define BMSK  127
#define MAXB  1024          // >= B = ceil(100000/128) = 782
#define ROST  (MAXB + 1)    // runoff row stride
#define CHUNK 4096
#define EPTH  16            // edges per thread = CHUNK/256
#define MAXCH 1024          // >= nchunk = ceil(E/CHUNK) = 782
#define BCAP  5120          // bucket stage cap (mean 4096, sd 64 -> +16sd)

// Sort chunk k by dst-bucket; edge data held in REGISTERS between passes.
// NO global atomics anywhere.
__global__ __launch_bounds__(256) void k_scatter(const int* __restrict__ src,
                                                 const int* __restrict__ dst,
                                                 int* __restrict__ runoff,
                                                 int* __restrict__ packed,
                                                 int E, int B) {
  __shared__ int sorted[CHUNK];
  __shared__ int hist[MAXB];
  __shared__ int wsum[4];
  int t = threadIdx.x;
  int k = blockIdx.x;
  int e0 = k * CHUNK;
  int cnt = min(CHUNK, E - e0);
  for (int b = t; b < B; b += 256) hist[b] = 0;
  __syncthreads();
  int pk[EPTH];
  int bk[EPTH];
  int base = t * EPTH;          // this thread's 16 consecutive edges
  int nloc = min(EPTH, max(0, cnt - base));
  if (cnt == CHUNK) {
    const int4* s4 = (const int4*)(src + e0 + base);
    const int4* d4 = (const int4*)(dst + e0 + base);
#pragma unroll
    for (int g = 0; g < 4; ++g) {
      int4 sv = s4[g];
      int4 dv = d4[g];
      pk[4 * g + 0] = (sv.x << BSH) | (dv.x & BMSK); bk[4 * g + 0] = dv.x >> BSH;
      pk[4 * g + 1] = (sv.y << BSH) | (dv.y & BMSK); bk[4 * g + 1] = dv.y >> BSH;
      pk[4 * g + 2] = (sv.z << BSH) | (dv.z & BMSK); bk[4 * g + 2] = dv.z >> BSH;
      pk[4 * g + 3] = (sv.w << BSH) | (dv.w & BMSK); bk[4 * g + 3] = dv.w >> BSH;
      atomicAdd(&hist[bk[4 * g + 0]], 1);
      atomicAdd(&hist[bk[4 * g + 1]], 1);
      atomicAdd(&hist[bk[4 * g + 2]], 1);
      atomicAdd(&hist[bk[4 * g + 3]], 1);
    }
  } else {
    for (int q = 0; q < nloc; ++q) {
      int d = dst[e0 + base + q], s = src[e0 + base + q];
      pk[q] = (s << BSH) | (d & BMSK);
      bk[q] = d >> BSH;
      atomicAdd(&hist[bk[q]], 1);
    }
  }
  __syncthreads();
  // block scan over B bins (256 threads x 4)
  int i0 = t * 4;
  int v0 = (i0 + 0 < B) ? hist[i0 + 0] : 0;
  int v1 = (i0 + 1 < B) ? hist[i0 + 1] : 0;
  int v2 = (i0 + 2 < B) ? hist[i0 + 2] : 0;
  int v3 = (i0 + 3 < B) ? hist[i0 + 3] : 0;
  int tsum = v0 + v1 + v2 + v3;
  int lane = t & 63, wid = t >> 6;
  int x = tsum;
#pragma unroll
  for (int d = 1; d < 64; d <<= 1) {
    int y = __shfl_up(x, d, 64);
    if (lane >= d) x += y;
  }
  if (lane == 63) wsum[wid] = x;
  __syncthreads();
  int wofs = 0;
  for (int ww = 0; ww < wid; ++ww) wofs += wsum[ww];
  int excl = wofs + x - tsum;
  hist[i0 + 0] = excl;
  hist[i0 + 1] = excl + v0;
  hist[i0 + 2] = excl + v0 + v1;
  hist[i0 + 3] = excl + v0 + v1 + v2;
  __syncthreads();
  // write run-offset row BEFORE cursors get bumped
  int* row = runoff + (size_t)k * ROST;
  for (int b = t; b < B; b += 256) row[b] = hist[b];
  if (t == 0) row[B] = cnt;
  __syncthreads();
  // pass 2: registers -> sorted[] via LDS cursors
#pragma unroll
  for (int q = 0; q < EPTH; ++q) {
    if (q < nloc) {
      int pos = atomicAdd(&hist[bk[q]], 1);
      sorted[pos] = pk[q];
    }
  }
  __syncthreads();
  // pass 3: coalesced sequential writeout (int4)
  if (cnt == CHUNK) {
    int4* po = (int4*)(packed + e0 + base);
    const int4* so = (const int4*)(sorted + base);
#pragma unroll
    for (int g = 0; g < 4; ++g) po[g] = so[g];
  } else {
    for (int i = t; i < cnt; i += 256) packed[e0 + i] = sorted[i];
  }
}

// Tiled transpose: AT[b][k] = A[k][b].
__global__ __launch_bounds__(256) void k_transpose(const int* __restrict__ A,
                                                   int* __restrict__ AT,
                                                   int rows, int cols) {
  __shared__ int tile[32][33];
  int bx = blockIdx.x * 32;
  int by = blockIdx.y * 32;
  int tx = threadIdx.x & 31, ty = threadIdx.x >> 5;
#pragma unroll
  for (int q = 0; q < 4; ++q) {
    int r = by + ty + q * 8, c = bx + tx;
    if (r < rows && c < cols) tile[ty + q * 8][tx] = A[(size_t)r * ROST + c];
  }
  __syncthreads();
#pragma unroll
  for (int q = 0; q < 4; ++q) {
    int c = bx + ty + q * 8;
    int r = by + tx;
    if (c < cols && r < rows) AT[(size_t)c * MAXCH + r] = tile[tx][ty + q * 8];
  }
}

// Per-bucket totals from the transposed run table: btot[b] = sum_k len(k,b).
// One wave per bucket; lanes stride k (coalesced); shuffle reduce. No atomics.
__global__ __launch_bounds__(256) void k_bsum(const int* __restrict__ runoffT,
                                              int* __restrict__ btot,
                                              int B, int nchunk) {
  int b = (blockIdx.x * blockDim.x + threadIdx.x) >> 6;
  int lane = threadIdx.x & 63;
  if (b >= B) return;
  const int* r0 = runoffT + (size_t)b * MAXCH;
  const int* r1 = runoffT + (size_t)(b + 1) * MAXCH;
  int s = 0;
  for (int k = lane; k < nchunk; k += 64) s += r1[k] - r0[k];
#pragma unroll
  for (int d = 32; d >= 1; d >>= 1) s += __shfl_down(s, d, 64);
  if (lane == 0) btot[b] = s;
}

// Exclusive scan of bucket totals -> bbase[0..B], bbase[B]=E. One block.
__global__ __launch_bounds__(1024) void k_btot(const int* __restrict__ btot,
                                               int* __restrict__ bbase,
                                               int B, int E) {
  __shared__ int wsum[16];
  int t = threadIdx.x;
  int c = (t < B) ? btot[t] : 0;
  int lane = t & 63, wid = t >> 6;
  int x = c;
#pragma unroll
  for (int d = 1; d < 64; d <<= 1) {
    int y = __shfl_up(x, d, 64);
    if (lane >= d) x += y;
  }
  if (lane == 63) wsum[wid] = x;
  __syncthreads();
  int wofs = 0;
  for (int ww = 0; ww < wid; ++ww) wofs += wsum[ww];
  if (t < B) bbase[t] = wofs + x - c;
  if (t == 0) bbase[B] = E;
}

// Per-bucket finalize, single pass: stage runs in LDS -> count -> scan ->
// off/dinv -> LDS node-scatter -> coalesced csr writeout.
__global__ __launch_bounds__(256) void k_bfin3(const int* __restrict__ packed,
                                               const int* __restrict__ runoffT,
                                               const int* __restrict__ bbase,
                                               int* __restrict__ off,
                                               float* __restrict__ dinv,
                                               int* __restrict__ csr,
                                               int N, int B, int nchunk) {
  __shared__ int rs[MAXCH];
  __shared__ unsigned short rl[MAXCH];
  __shared__ int pref[MAXCH];
  __shared__ int stage[BCAP];
  __shared__ int sortedL[BCAP];
  __shared__ int cntL[NPB];
  __shared__ int curL[NPB];
  __shared__ int wsum[4];
  int t = threadIdx.x;
  int b = blockIdx.x;
  for (int k = t; k < nchunk; k += 256) {
    int s = runoffT[(size_t)b * MAXCH + k];
    int e = runoffT[(size_t)(b + 1) * MAXCH + k];
    rs[k] = k * CHUNK + s;
    rl[k] = (unsigned short)(e - s);
  }
  if (t < NPB) cntL[t] = 0;
  __syncthreads();
  int i0 = t * 4;
  int v0 = (i0 + 0 < nchunk) ? rl[i0 + 0] : 0;
  int v1 = (i0 + 1 < nchunk) ? rl[i0 + 1] : 0;
  int v2 = (i0 + 2 < nchunk) ? rl[i0 + 2] : 0;
  int v3 = (i0 + 3 < nchunk) ? rl[i0 + 3] : 0;
  int tsum = v0 + v1 + v2 + v3;
  int lane = t & 63, w = t >> 6;
  int x = tsum;
#pragma unroll
  for (int d = 1; d < 64; d <<= 1) {
    int y = __shfl_up(x, d, 64);
    if (lane >= d) x += y;
  }
  if (lane == 63) wsum[w] = x;
  __syncthreads();
  int wofs = 0;
  for (int ww = 0; ww < w; ++ww) wofs += wsum[ww];
  int excl = wofs + x - tsum;
  pref[i0 + 0] = excl;
  pref[i0 + 1] = excl + v0;
  pref[i0 + 2] = excl + v0 + v1;
  pref[i0 + 3] = excl + v0 + v1 + v2;
  __syncthreads();
  int wbase = bbase[b];
  int total = bbase[b + 1] - wbase;
  bool inLDS = (total <= BCAP);
  if (inLDS) {
    for (int k = t; k < nchunk; k += 256) {
      int base = rs[k], len = rl[k], o = pref[k];
      for (int j = 0; j < len; ++j) stage[o + j] = packed[base + j];
    }
    __syncthreads();
    for (int i = t; i < total; i += 256)
      atomicAdd(&cntL[stage[i] & BMSK], 1);
  } else {
    for (int k = t; k < nchunk; k += 256) {
      int base = rs[k], len = rl[k];
      for (int j = 0; j < len; ++j)
        atomicAdd(&cntL[packed[base + j] & BMSK], 1);
    }
  }
  __syncthreads();
  int c = (t < NPB) ? cntL[t] : 0;
  x = c;
#pragma unroll
  for (int d = 1; d < 64; d <<= 1) {
    int y = __shfl_up(x, d, 64);
    if (lane >= d) x += y;
  }
  if (lane == 63) wsum[w] = x;
  __syncthreads();
  wofs = 0;
  for (int ww = 0; ww < w; ++ww) wofs += wsum[ww];
  int nexcl = wofs + x - c;
  int v = (b << BSH) + t;
  if (t < NPB && v < N) {
    off[v] = wbase + nexcl;
    dinv[v] = rsqrtf((float)(c + 1));  // +1 self-loop
  }
  if (t < NPB) curL[t] = inLDS ? nexcl : (wbase + nexcl);
  if (b == B - 1 && t == 0) off[N] = bbase[B];
  __syncthreads();
  if (inLDS) {
    for (int i = t; i < total; i += 256) {
      int e = stage[i];
      int p = atomicAdd(&curL[e & BMSK], 1);
      sortedL[p] = e >> BSH;
    }
    __syncthreads();
    for (int i = t; i < total; i += 256) csr[wbase + i] = sortedL[i];
  } else {
    for (int k = t; k < nchunk; k += 256) {
      int base = rs[k], len = rl[k];
      for (int j = 0; j < len; ++j) {
        int e = packed[base + j];
        int p = atomicAdd(&curL[e & BMSK], 1);
        csr[p] = e >> BSH;
      }
    }
  }
}

// H'[v] = fp16((X @ W)[v] * dinv[v]).  W (16KB) in LDS; 8 nodes/block-iter.
__global__ __launch_bounds__(256) void k_gemm64(const float* __restrict__ X,
                                                const float* __restrict__ W,
                                                const float* __restrict__ dinv,
                                                __half* __restrict__ H, int N) {
  __shared__ float Wl[4096];
  __shared__ float Xl[512];
  for (int t = threadIdx.x; t < 4096; t += 256) Wl[t] = W[t];
  int j = threadIdx.x & 63;
  int nl = threadIdx.x >> 6;
  for (int base = blockIdx.x * 8; base < N; base += gridDim.x * 8) {
    __syncthreads();
    int gi = base * 64 + threadIdx.x;
    Xl[threadIdx.x] = (gi < N * 64) ? X[gi] : 0.f;
    int gi2 = gi + 256;
    Xl[threadIdx.x + 256] = (gi2 < N * 64) ? X[gi2] : 0.f;
    __syncthreads();
#pragma unroll
    for (int q = 0; q < 2; ++q) {
      int v = base + nl + q * 4;
      if (v < N) {
        const float* xr = &Xl[(nl + q * 4) * 64];
        float acc = 0.f;
#pragma unroll
        for (int k = 0; k < 64; k += 4) {
          acc = fmaf(xr[k + 0], Wl[(k + 0) * 64 + j], acc);
          acc = fmaf(xr[k + 1], Wl[(k + 1) * 64 + j], acc);
          acc = fmaf(xr[k + 2], Wl[(k + 2) * 64 + j], acc);
          acc = fmaf(xr[k + 3], Wl[(k + 3) * 64 + j], acc);
        }
        H[(size_t)v * 64 + j] = __float2half_rn(acc * dinv[v]);
      }
    }
  }
}

// Pull aggregation, dual-edge (benched R8 version, unchanged).
template <bool RELU>
__global__ __launch_bounds__(256) void k_agg(const __half* __restrict__ H,
                                             const int* __restrict__ csr,
                                             const int* __restrict__ off,
                                             const float* __restrict__ dinv,
                                             const float* __restrict__ bias,
                                             float* __restrict__ out, int N) {
  int wid = (blockIdx.x * blockDim.x + threadIdx.x) >> 6;
  int lane = threadIdx.x & 63;
  if (wid >= N) return;
  int hl = lane & 31;
  int half = lane >> 5;
  int beg = off[wid];
  int num = off[wid + 1] - beg;
  const __half2* Hp = (const __half2*)H;
  float2 fs = __half22float2(Hp[(size_t)wid * 32 + hl]);
  float2 acc = half ? make_float2(0.f, 0.f) : fs;
  for (int base = 0; base < num; base += 64) {
    int navail = min(64, num - base);
    int sv = (base + lane < num) ? csr[beg + base + lane] : 0;
    int npair = navail >> 1;
    int i = 0;
    for (; i + 8 <= npair; i += 8) {
      int e0 = __shfl(sv, 2 * (i + 0) + half), e1 = __shfl(sv, 2 * (i + 1) + half);
      int e2 = __shfl(sv, 2 * (i + 2) + half), e3 = __shfl(sv, 2 * (i + 3) + half);
      int e4 = __shfl(sv, 2 * (i + 4) + half), e5 = __shfl(sv, 2 * (i + 5) + half);
      int e6 = __shfl(sv, 2 * (i + 6) + half), e7 = __shfl(sv, 2 * (i + 7) + half);
      float2 f0 = __half22float2(Hp[(size_t)e0 * 32 + hl]);
      float2 f1 = __half22float2(Hp[(size_t)e1 * 32 + hl]);
      float2 f2 = __half22float2(Hp[(size_t)e2 * 32 + hl]);
      float2 f3 = __half22float2(Hp[(size_t)e3 * 32 + hl]);
      float2 f4 = __half22float2(Hp[(size_t)e4 * 32 + hl]);
      float2 f5 = __half22float2(Hp[(size_t)e5 * 32 + hl]);
      float2 f6 = __half22float2(Hp[(size_t)e6 * 32 + hl]);
      float2 f7 = __half22float2(Hp[(size_t)e7 * 32 + hl]);
      acc.x += f0.x + f1.x + f2.x + f3.x;
      acc.y += f0.y + f1.y + f2.y + f3.y;
      acc.x += f4.x + f5.x + f6.x + f7.x;
      acc.y += f4.y + f5.y + f6.y + f7.y;
    }
    for (; i < npair; ++i) {
      int e = __shfl(sv, 2 * i + half);
      float2 f = __half22float2(Hp[(size_t)e * 32 + hl]);
      acc.x += f.x; acc.y += f.y;
    }
    if (navail & 1) {
      int e = __shfl(sv, navail - 1);
      if (!half) {
        float2 f = __half22float2(Hp[(size_t)e * 32 + hl]);
        acc.x += f.x; acc.y += f.y;
      }
    }
  }
  acc.x += __shfl_xor(acc.x, 32);
  acc.y += __shfl_xor(acc.y, 32);
  if (!half) {
    float dv = dinv[wid];
    float2 bb = ((const float2*)bias)[hl];
    float2 r;
    r.x = fmaf(acc.x, dv, bb.x);
    r.y = fmaf(acc.y, dv, bb.y);
    if (RELU) { r.x = fmaxf(r.x, 0.f); r.y = fmaxf(r.y, 0.f); }
    ((float2*)(out + (size_t)wid * 64))[hl] = r;
  }
}

extern "C" void kernel_launch(void* const* d_in, const int* in_sizes, int n_in,
                              void* d_out, int out_size, void* d_ws, size_t ws_size,
                              hipStream_t stream) {
  const float* x  = (const float*)d_in[0];
  const float* W1 = (const float*)d_in[1];
  const float* b1 = (const float*)d_in[2];
  const float* W2 = (const float*)d_in[3];
  const float* b2 = (const float*)d_in[4];
  const int*   e0 = (const int*)d_in[5];
  const int*   e1 = (const int*)d_in[6];
  float* out = (float*)d_out;

  const int N = in_sizes[0] / 64;      // 100000
  const int E = in_sizes[5] / 2;       // 3200000
  const int B = (N + NPB - 1) / NPB;   // 782
  const int nchunk = (E + CHUNK - 1) / CHUNK;  // 782
  const int* src0 = e0;     const int* dst0 = e0 + E;
  const int* src1 = e1;     const int* dst1 = e1 + E;

  char* w = (char*)d_ws;
  size_t o = 0;
  auto carve = [&](size_t bytes) -> void* {
    void* p = w + o;
    o = (o + bytes + 255) & ~(size_t)255;
    return p;
  };
  int* btot = (int*)carve((size_t)MAXB * 4);
  int* bbase = (int*)carve((MAXB + 1) * 4);
  int* runoff = (int*)carve((size_t)MAXCH * ROST * 4);        // shared
  int* runoffT = (int*)carve((size_t)(MAXB + 1) * MAXCH * 4); // shared
  int* off = (int*)carve((size_t)(N + 1) * 4);     // shared (serialized)
  float* dinv = (float*)carve((size_t)N * 4);      // shared (serialized)
  int* packed = (int*)carve((size_t)nchunk * CHUNK * 4);  // shared
  int* csr = (int*)carve((size_t)E * 4);           // shared (serialized)
  __half* H = (__half*)carve((size_t)N * 64 * 2);

  const int aggblk = (N * 64 + 255) / 256;  // 25000
  const int bsumblk = (B * 64 + 255) / 256; // 196
  const dim3 tgrid((B + 1 + 31) / 32, (nchunk + 31) / 32);

  // layer 1
  k_scatter<<<nchunk, 256, 0, stream>>>(src0, dst0, runoff, packed, E, B);
  k_transpose<<<tgrid, 256, 0, stream>>>(runoff, runoffT, nchunk, B + 1);
  k_bsum<<<bsumblk, 256, 0, stream>>>(runoffT, btot, B, nchunk);
  k_btot<<<1, 1024, 0, stream>>>(btot, bbase, B, E);
  k_bfin3<<<B, 256, 0, stream>>>(packed, runoffT, bbase, off, dinv, csr, N, B, nchunk);
  k_gemm64<<<2048, 256, 0, stream>>>(x, W1, dinv, H, N);
  k_agg<true><<<aggblk, 256, 0, stream>>>(H, csr, off, dinv, b1, out, N);

  // layer 2 (all scratch reused; stream order serializes)
  k_scatter<<<nchunk, 256, 0, stream>>>(src1, dst1, runoff, packed, E, B);
  k_transpose<<<tgrid, 256, 0, stream>>>(runoff, runoffT, nchunk, B + 1);
  k_bsum<<<bsumblk, 256, 0, stream>>>(runoffT, btot, B, nchunk);
  k_btot<<<1, 1024, 0, stream>>>(btot, bbase, B, E);
  k_bfin3<<<B, 256, 0, stream>>>(packed, runoffT, bbase, off, dinv, csr, N, B, nchunk);
  k_gemm64<<<2048, 256, 0, stream>>>(out, W2, dinv, H, N);
  k_agg<false><<<aggblk, 256, 0, stream>>>(H, csr, off, dinv, b2, out, N);
}